// Round 16
// baseline (144.982 us; speedup 1.0000x reference)
//
#include <hip/hip_runtime.h>
#include <math.h>

typedef _Float16 f16x8 __attribute__((ext_vector_type(8)));
typedef _Float16 f16x4 __attribute__((ext_vector_type(4)));
typedef float    f32x16 __attribute__((ext_vector_type(16)));
typedef unsigned int u32;

#define DEVINL __device__ __forceinline__

DEVINL float fast_sigmoid(float x) {
    x = fminf(fmaxf(x, -30.f), 30.f);
    return 1.0f / (1.0f + __expf(-x));
}
DEVINL float fast_tanh(float x) {
    x = fminf(fmaxf(x, -15.f), 15.f);
    float e = __expf(-2.f * x);
    return (1.f - e) / (1.f + e);
}
DEVINL f16x8 f16x8_zero() {
    f16x8 v;
    #pragma unroll
    for (int j = 0; j < 8; ++j) v[j] = (_Float16)0.f;
    return v;
}

#define TKY(t) ((t) < 25 ? (t) / 5 : 2)
#define TKX(t) ((t) < 25 ? (t) % 5 : 2)

union PK { _Float16 h[2]; u32 u; };

// ---------------------------------------------------------------------------
// k1: conv 1->4 + relu + maxpool2 as MFMA, TWO pooled rows folded into M.
//   m = rp*16 + oc*4 + pos (all 32 M rows used), K = 64 (8 in-rows x 8 cols).
//   Per 64 output px: 16 ds_read + 4 MFMA (was 24 + 6) -- k1 is
//   instruction-bound on the B-gather (r13-r15 evidence), this cuts it 33%.
//   block = 1 img x 4 pooled rows; wave w: row-pair pi=w>>1, col-half w&1.
//   Staging (12 rows x 264 f16, pitch 132 u32) verbatim from r15-verified.
// ---------------------------------------------------------------------------
__global__ __launch_bounds__(256, 4) void k1_mfma(
    const float* __restrict__ obs, const float* __restrict__ w1,
    const float* __restrict__ w2, const float* __restrict__ wx,
    const float* __restrict__ wh, const float* __restrict__ bx,
    const float* __restrict__ bh, const float* __restrict__ b1,
    _Float16* __restrict__ w2F, _Float16* __restrict__ wxF,
    _Float16* __restrict__ whF, float* __restrict__ btot,
    _Float16* __restrict__ s1cl)
{
    __shared__ _Float16 lds[12 * 264];       // 6,336 B, pitch 132 u32
    u32* ldsu = (u32*)lds;
    int tid = threadIdx.x;
    int lane = tid & 63, w = tid >> 6, g = lane >> 5;
    int yt = blockIdx.x & 31;                // band: 4 pooled rows
    int tb = blockIdx.x >> 5;
    const float* in = obs + ((size_t)tb << 16);

    if (blockIdx.x == 0) {                   // downstream weight frags (no kT)
        for (int i = tid; i < 12 * 512; i += 256) {      // w2F
            int j = i & 7, l = (i >> 3) & 63, q = i >> 9;
            int gg = l >> 5, m = l & 31;
            int k = q * 16 + gg * 8 + j;
            int pr = k >> 5, pc = (k >> 2) & 7, ic = k & 3;
            float v = 0.f;
            if (m < 16) {
                int oc = m >> 2, qy = (m >> 1) & 1, qx = m & 1;
                int ky = pr - qy, kx = pc - qx;
                if ((unsigned)ky < 5u && (unsigned)kx < 5u)
                    v = w2[(oc * 4 + ic) * 25 + ky * 5 + kx];
            }
            w2F[i] = (_Float16)v;
        }
        for (int i = tid; i < 10 * 512; i += 256) {      // wxF
            int j = i & 7, l = (i >> 3) & 63, q = i >> 9;
            int gg = l >> 5, m = l & 31;
            int k = q * 16 + gg * 8 + j;
            int pr = k >> 5, pc = (k >> 2) & 7, ic = k & 3;
            int og = (m & 3) * 8 + (m >> 2);
            float v = (pr < 5 && pc < 5) ? wx[(og * 4 + ic) * 25 + pr * 5 + pc] : 0.f;
            wxF[i] = (_Float16)v;
        }
        for (int i = tid; i < 14 * 512; i += 256) {      // whF (j = ch' order)
            int j = i & 7, l = (i >> 3) & 63, q = i >> 9;
            int gg = l >> 5, m = l & 31;
            int og = (m & 3) * 8 + (m >> 2);
            int tap = 2 * q + gg;
            int icj = 2 * (j & 3) + (j >> 2);
            float v = (tap < 25) ? wh[(og * 8 + icj) * 25 + tap] : 0.f;
            whF[i] = (_Float16)v;
        }
        if (tid < 32) {
            int og = (tid & 3) * 8 + (tid >> 2);
            btot[tid] = bx[og] + bh[og];
        }
    }

    // A-fragments: m = rp*16 + oc*4 + pos; chunk q: ir=2q+g, jc=j
    f16x8 wk1[4];
    {
        int m = lane & 31;
        int rp = m >> 4, oc = (m >> 2) & 3, qy = (m >> 1) & 1, qx = m & 1;
        #pragma unroll
        for (int q = 0; q < 4; ++q) {
            #pragma unroll
            for (int j = 0; j < 8; ++j) {
                int ky = 2 * q + g - 2 * rp - qy;
                int kx = j - qx;
                float v = 0.f;
                if ((unsigned)ky < 5u && (unsigned)kx < 5u)
                    v = w1[oc * 25 + ky * 5 + kx];
                wk1[q][j] = (_Float16)v;
            }
        }
    }
    asm volatile("" : "+v"(wk1[0]), "+v"(wk1[1]), "+v"(wk1[2]), "+v"(wk1[3]));
    float bA = b1[g], bB = b1[g + 2];

    // stage input rows 8yt-2 .. 8yt+9 (12 rows), zero-padded
    for (int i = tid; i < 12 * 64; i += 256) {
        int r = i >> 6, c4 = i & 63;
        int gy = (yt << 3) - 2 + r;
        float4 v = make_float4(0.f, 0.f, 0.f, 0.f);
        if ((unsigned)gy < 256u)
            v = *(const float4*)(in + (gy << 8) + (c4 << 2));
        PK p0, p1;
        p0.h[0] = (_Float16)v.x; p0.h[1] = (_Float16)v.y;
        p1.h[0] = (_Float16)v.z; p1.h[1] = (_Float16)v.w;
        int ui = r * 132 + 1 + 2 * c4;
        ldsu[ui]     = p0.u;
        ldsu[ui + 1] = p1.u;
    }
    if (tid < 48) {    // halo u32s {0,129,130,131} per row
        int r = tid >> 2, c = tid & 3;
        int idx = (c == 0) ? 0 : 128 + c;
        ldsu[r * 132 + idx] = 0;
    }
    __syncthreads();

    // wave w: row-pair pi = w>>1 (pooled rows 4yt+2pi, +1), col-half ch = w&1
    int pi = w >> 1, ch = w & 1;
    int py0 = (yt << 2) + (pi << 1);
    #pragma unroll
    for (int i = 0; i < 2; ++i) {
        int n = (ch << 6) + (i << 5) + (lane & 31);   // pooled col 0..127
        const u32* lp = ldsu + ((pi << 2) + g) * 132 + n;

        f32x16 acc;
        #pragma unroll
        for (int r = 0; r < 16; ++r) acc[r] = 0.f;

        #pragma unroll
        for (int q = 0; q < 4; ++q) {
            union { f16x8 v; u32 u[4]; } bb;
            const u32* p = lp + (2 * q) * 132;
            bb.u[0] = p[0]; bb.u[1] = p[1]; bb.u[2] = p[2]; bb.u[3] = p[3];
            acc = __builtin_amdgcn_mfma_f32_32x32x16_f16(wk1[q], bb.v, acc, 0, 0, 0);
        }

        // rp0 -> acc[0..7], rp1 -> acc[8..15]
        #pragma unroll
        for (int rp = 0; rp < 2; ++rp) {
            float mA = fmaxf(fmaxf(fmaxf(acc[8 * rp + 0], acc[8 * rp + 1]),
                                   fmaxf(acc[8 * rp + 2], acc[8 * rp + 3])) + bA, 0.f);
            float mB = fmaxf(fmaxf(fmaxf(acc[8 * rp + 4], acc[8 * rp + 5]),
                                   fmaxf(acc[8 * rp + 6], acc[8 * rp + 7])) + bB, 0.f);
            PK pk;
            pk.h[0] = (_Float16)mA;
            pk.h[1] = (_Float16)mB;
            u32 part = (u32)__shfl_xor((int)pk.u, 32);
            if (g == 0) {
                PK pp; pp.u = part;
                f16x4 ov;
                ov[0] = pk.h[0]; ov[1] = pp.h[0];
                ov[2] = pk.h[1]; ov[3] = pp.h[1];
                int pix = ((py0 + rp) << 7) + n;
                *(f16x4*)(s1cl + (((size_t)tb << 14) + pix) * 4) = ov;
            }
        }
    }
}

// ---------------------------------------------------------------------------
// k2: conv 4->4 + relu + maxpool2 as MFMA (pool-in-M), coalesced store.
// ---------------------------------------------------------------------------
__global__ __launch_bounds__(256) void k2_mfma(
    const _Float16* __restrict__ s1cl, const _Float16* __restrict__ w2F,
    const float* __restrict__ b2, _Float16* __restrict__ s2cl)
{
    __shared__ _Float16 lds[20 * 136 * 4];
    int tid = threadIdx.x;
    int lane = tid & 63, w = tid >> 6, g = lane >> 5;
    int f  = blockIdx.x >> 3;
    int yt = blockIdx.x & 7;
    int y0 = yt << 3;

    f16x8 wf[12];
    #pragma unroll
    for (int q = 0; q < 12; ++q)
        wf[q] = *(const f16x8*)(w2F + ((size_t)q * 64 + lane) * 8);

    float bA = b2[g], bB = b2[g + 2];

    for (int i = tid; i < 20 * 68; i += 256) {
        int r = i / 68, u = i % 68;
        int gy = (yt << 4) - 2 + r;
        int gx = 2 * u - 2;
        f16x8 v = f16x8_zero();
        if ((unsigned)gy < 128u && (unsigned)gx < 127u)
            v = *(const f16x8*)(s1cl + ((((size_t)f << 14) + (gy << 7) + gx) << 2));
        *(f16x8*)&lds[(r * 136 + 2 * u) * 4] = v;
    }
    __syncthreads();

    #pragma unroll
    for (int i = 0; i < 4; ++i) {
        int ct = w * 4 + i;
        int ly = ct >> 1, hx = ct & 1;
        int px = hx * 32 + (lane & 31);
        int base = (2 * ly) * 1088 + (2 * px) * 8 + g * 16;

        f32x16 acc;
        #pragma unroll
        for (int r = 0; r < 16; ++r) acc[r] = 0.f;

        #pragma unroll
        for (int q = 0; q < 12; ++q) {
            f16x8 bv = *(const f16x8*)((const char*)lds + base +
                                       ((q >> 1) * 1088 + (q & 1) * 32));
            acc = __builtin_amdgcn_mfma_f32_32x32x16_f16(wf[q], bv, acc, 0, 0, 0);
        }

        float mA = fmaxf(fmaxf(fmaxf(acc[0], acc[1]), fmaxf(acc[2], acc[3])) + bA, 0.f);
        float mB = fmaxf(fmaxf(fmaxf(acc[4], acc[5]), fmaxf(acc[6], acc[7])) + bB, 0.f);

        PK pk;
        pk.h[0] = (_Float16)mA;
        pk.h[1] = (_Float16)mB;
        u32 part = (u32)__shfl_xor((int)pk.u, 32);
        if (g == 0) {
            PK pp; pp.u = part;
            f16x4 ov;
            ov[0] = pk.h[0]; ov[1] = pp.h[0];
            ov[2] = pk.h[1]; ov[3] = pp.h[1];
            int pix = ((y0 + ly) << 6) + px;
            *(f16x4*)(s2cl + ((((size_t)f << 12) + pix) << 2)) = ov;
        }
    }
}

// ---------------------------------------------------------------------------
// k4x: one ConvLSTM step with k3 fused (r12 verified), `first` flag skips
// state reads (no zero-init memsets anywhere).
// ---------------------------------------------------------------------------
__global__ __launch_bounds__(256, 4) void k4x(
    const _Float16* __restrict__ s2t, const _Float16* __restrict__ hprev,
    const _Float16* __restrict__ wxF, const _Float16* __restrict__ whF,
    const float* __restrict__ btot, float* __restrict__ cfr,
    const float* __restrict__ wci, const float* __restrict__ wcf,
    const float* __restrict__ wco, _Float16* __restrict__ hnext,
    float* __restrict__ out_hc, int first, int last)
{
    __shared__ _Float16 sH[6 * 68 * 8];      // 6528 B, pitch 1088
    __shared__ _Float16 sS[6 * 72 * 4];      // 3456 B, pitch 576
    int tid = threadIdx.x;
    int lane = tid & 63, w = tid >> 6, g = lane >> 5;
    int b  = blockIdx.x >> 5;
    int y0 = (blockIdx.x & 31) << 1;

    int ly = w >> 1, hx = w & 1;
    int px = hx * 32 + (lane & 31);
    int pix = ((y0 + ly) << 6) + px;
    size_t tl = (size_t)b * 128 + (y0 + ly) * 2 + hx;

    float4 cv = make_float4(0.f, 0.f, 0.f, 0.f);
    if (!first) cv = *(const float4*)(cfr + tl * 256 + lane * 4);
    float pci[4], pcf[4], pco[4];
    #pragma unroll
    for (int cc = 0; cc < 4; ++cc) {
        int ppix = ((2 * cc + g) << 12) + pix;
        pci[cc] = wci[ppix];
        pcf[cc] = wcf[ppix];
        pco[cc] = wco[ppix];
    }

    for (int i = tid; i < 6 * 68; i += 256) {
        int r = i / 68, u = i % 68;
        int gy = y0 - 2 + r;
        int gx = u - 2;
        f16x8 v = f16x8_zero();
        if (!first && (unsigned)gy < 64u && (unsigned)gx < 64u)
            v = *(const f16x8*)(hprev + ((((size_t)b << 12) + (gy << 6) + gx) << 3));
        *(f16x8*)&sH[(r * 68 + u) * 8] = v;
    }
    for (int i = tid; i < 6 * 36; i += 256) {
        int r = i / 36, u = i % 36;
        int gy = y0 - 2 + r;
        int gx = 2 * u - 2;
        f16x8 v = f16x8_zero();
        if ((unsigned)gy < 64u && (unsigned)gx < 63u)
            v = *(const f16x8*)(s2t + ((((size_t)b << 12) + (gy << 6) + gx) << 2));
        *(f16x8*)&sS[(r * 72 + 2 * u) * 4] = v;
    }
    __syncthreads();

    f32x16 acc;
    #pragma unroll
    for (int r = 0; r < 16; ++r) {
        int row0 = (r & 3) + 8 * (r >> 2);
        acc[r] = g ? btot[row0 + 4] : btot[row0];
    }

    {
        int baseS = ly * 576 + px * 8 + g * 16;
        #pragma unroll
        for (int q = 0; q < 10; ++q) {
            f16x8 wv = *(const f16x8*)(wxF + ((size_t)q * 64 + lane) * 8);
            f16x8 bv = *(const f16x8*)((const char*)sS + baseS +
                                       ((q >> 1) * 576 + (q & 1) * 32));
            acc = __builtin_amdgcn_mfma_f32_32x32x16_f16(wv, bv, acc, 0, 0, 0);
        }
    }
    {
        int baseH = ly * 1088 + px * 16;
        #pragma unroll
        for (int q = 0; q < 14; ++q) {
            int t0 = 2 * q, t1 = 2 * q + 1;
            int o0 = TKY(t0) * 1088 + TKX(t0) * 16;
            int o1 = TKY(t1) * 1088 + TKX(t1) * 16;
            int toff = g ? o1 : o0;
            f16x8 wv = *(const f16x8*)(whF + ((size_t)q * 64 + lane) * 8);
            f16x8 bv = *(const f16x8*)((const char*)sH + baseH + toff);
            acc = __builtin_amdgcn_mfma_f32_32x32x16_f16(wv, bv, acc, 0, 0, 0);
        }
    }

    float cvv[4] = {cv.x, cv.y, cv.z, cv.w};
    float cn4[4];
    f16x4 hv;
    #pragma unroll
    for (int cc = 0; cc < 4; ++cc) {
        float c_old = cvv[cc];
        float i_ = fast_sigmoid(acc[4 * cc + 0] + c_old * pci[cc]);
        float f_ = fast_sigmoid(acc[4 * cc + 1] + c_old * pcf[cc]);
        float cn = f_ * c_old + i_ * fast_tanh(acc[4 * cc + 2]);
        float o_ = fast_sigmoid(acc[4 * cc + 3] + cn * pco[cc]);
        float hn = o_ * fast_tanh(cn);
        cn4[cc] = cn;
        hv[cc] = (_Float16)hn;
        if (last) {
            int ch = 2 * cc + g;
            size_t sidx = (((size_t)b * 8 + ch) << 12) + pix;
            out_hc[sidx] = hn;
            out_hc[sidx + 1048576] = cn;
        }
    }
    if (!last) {
        *(float4*)(cfr + tl * 256 + lane * 4) =
            make_float4(cn4[0], cn4[1], cn4[2], cn4[3]);
        *(f16x4*)(hnext + ((((size_t)b << 12) + pix) << 3) + 4 * g) = hv;
    }
}

// ---------------------------------------------------------------------------
extern "C" void kernel_launch(void* const* d_in, const int* in_sizes, int n_in,
                              void* d_out, int out_size, void* d_ws, size_t ws_size,
                              hipStream_t stream)
{
    const float* obs = (const float*)d_in[0];
    const float* w1  = (const float*)d_in[1];
    const float* b1  = (const float*)d_in[2];
    const float* w2  = (const float*)d_in[3];
    const float* b2  = (const float*)d_in[4];
    const float* wx  = (const float*)d_in[5];
    const float* bx  = (const float*)d_in[6];
    const float* wh  = (const float*)d_in[7];
    const float* bh  = (const float*)d_in[8];
    const float* wci = (const float*)d_in[9];
    const float* wcf = (const float*)d_in[10];
    const float* wco = (const float*)d_in[11];

    char* wsb = (char*)d_ws;
    // byte layout:
    //   [0, 33,554,432)             s1cl f16 [256][16384][4]
    //   [33,554,432, 41,943,040)    s2cl f16 [256][4096][4]
    //   [41,943,040, 44,040,192)    hA f16
    //   [44,040,192, 46,137,344)    hB f16
    //   [46,137,344, 50,331,648)    cfr f32 [4096 tl][64][4]
    //   [50,331,648, ...)           w2F, wxF, whF, btot
    _Float16* s1cl = (_Float16*)wsb;
    _Float16* s2cl = (_Float16*)(wsb + 33554432);
    _Float16* hA   = (_Float16*)(wsb + 41943040);
    _Float16* hB   = (_Float16*)(wsb + 44040192);
    float*    cfr  = (float*)(wsb + 46137344);
    _Float16* w2F  = (_Float16*)(wsb + 50331648);
    _Float16* wxF  = (_Float16*)(wsb + 50343936);
    _Float16* whF  = (_Float16*)(wsb + 50354176);
    float*    btot = (float*)(wsb + 50368512);

    k1_mfma<<<8192, 256, 0, stream>>>(obs, w1, w2, wx, wh, bx, bh, b1,
                                      w2F, wxF, whF, btot, s1cl);
    k2_mfma<<<2048, 256, 0, stream>>>(s1cl, w2F, b2, s2cl);

    float* outp = (float*)d_out;
    for (int t = 0; t < 8; ++t) {
        const _Float16* hp = (t & 1) ? hB : hA;
        _Float16*       hn = (t & 1) ? hA : hB;
        k4x<<<1024, 256, 0, stream>>>(
            s2cl + (size_t)t * 524288, hp, wxF, whF, btot, cfr,
            wci, wcf, wco, hn, outp, t == 0, t == 7);
    }
}

// Round 17
// 140.893 us; speedup vs baseline: 1.0290x; 1.0290x over previous
//
#include <hip/hip_runtime.h>
#include <math.h>

typedef _Float16 f16x8 __attribute__((ext_vector_type(8)));
typedef _Float16 f16x4 __attribute__((ext_vector_type(4)));
typedef float    f32x16 __attribute__((ext_vector_type(16)));
typedef unsigned int u32;

#define DEVINL __device__ __forceinline__

DEVINL float fast_sigmoid(float x) {
    x = fminf(fmaxf(x, -30.f), 30.f);
    return 1.0f / (1.0f + __expf(-x));
}
DEVINL float fast_tanh(float x) {
    x = fminf(fmaxf(x, -15.f), 15.f);
    float e = __expf(-2.f * x);
    return (1.f - e) / (1.f + e);
}
DEVINL f16x8 f16x8_zero() {
    f16x8 v;
    #pragma unroll
    for (int j = 0; j < 8; ++j) v[j] = (_Float16)0.f;
    return v;
}

#define TKY(t) ((t) < 25 ? (t) / 5 : 2)
#define TKX(t) ((t) < 25 ? (t) % 5 : 2)

union PK { _Float16 h[2]; u32 u; };

// ---------------------------------------------------------------------------
// k1: conv 1->4 + relu + maxpool2 as MFMA (pool-in-M), r15 structure
// (4 tiles/wave — best measured at ~40.7us on clean dispatches).
// Weight prep for downstream kernels is DISTRIBUTED over blocks 0..36
// (one 512-elem slice per block, 2 f16/thread) instead of serialized in
// block 0 — r13-r16 showed block-0 prep added 6-10us to the kernel tail.
// ---------------------------------------------------------------------------
__global__ __launch_bounds__(256, 4) void k1_mfma(
    const float* __restrict__ obs, const float* __restrict__ w1,
    const float* __restrict__ w2, const float* __restrict__ wx,
    const float* __restrict__ wh, const float* __restrict__ bx,
    const float* __restrict__ bh, const float* __restrict__ b1,
    _Float16* __restrict__ w2F, _Float16* __restrict__ wxF,
    _Float16* __restrict__ whF, float* __restrict__ btot,
    _Float16* __restrict__ s1cl)
{
    __shared__ _Float16 lds[12 * 264];       // 6,336 B, pitch 132 u32
    u32* ldsu = (u32*)lds;
    int tid = threadIdx.x;
    int lane = tid & 63, w = tid >> 6, g = lane >> 5;
    int yt = blockIdx.x & 31;                // band: 4 pooled rows
    int tb = blockIdx.x >> 5;
    const float* in = obs + ((size_t)tb << 16);

    // distributed weight prep: block b handles one 512-element slice
    {
        int b = blockIdx.x;
        if (b < 12) {                         // w2F slice q=b
            #pragma unroll
            for (int e = 0; e < 2; ++e) {
                int i = b * 512 + tid * 2 + e;
                int j = i & 7, l = (i >> 3) & 63, q = i >> 9;
                int gg = l >> 5, m = l & 31;
                int k = q * 16 + gg * 8 + j;
                int pr = k >> 5, pc = (k >> 2) & 7, ic = k & 3;
                float v = 0.f;
                if (m < 16) {
                    int oc = m >> 2, qy = (m >> 1) & 1, qx = m & 1;
                    int ky = pr - qy, kx = pc - qx;
                    if ((unsigned)ky < 5u && (unsigned)kx < 5u)
                        v = w2[(oc * 4 + ic) * 25 + ky * 5 + kx];
                }
                w2F[i] = (_Float16)v;
            }
        } else if (b < 22) {                  // wxF slice q=b-12
            #pragma unroll
            for (int e = 0; e < 2; ++e) {
                int i = (b - 12) * 512 + tid * 2 + e;
                int j = i & 7, l = (i >> 3) & 63, q = i >> 9;
                int gg = l >> 5, m = l & 31;
                int k = q * 16 + gg * 8 + j;
                int pr = k >> 5, pc = (k >> 2) & 7, ic = k & 3;
                int og = (m & 3) * 8 + (m >> 2);
                float v = (pr < 5 && pc < 5) ?
                          wx[(og * 4 + ic) * 25 + pr * 5 + pc] : 0.f;
                wxF[i] = (_Float16)v;
            }
        } else if (b < 36) {                  // whF slice q=b-22 (j=ch' order)
            #pragma unroll
            for (int e = 0; e < 2; ++e) {
                int i = (b - 22) * 512 + tid * 2 + e;
                int j = i & 7, l = (i >> 3) & 63, q = i >> 9;
                int gg = l >> 5, m = l & 31;
                int og = (m & 3) * 8 + (m >> 2);
                int tap = 2 * q + gg;
                int icj = 2 * (j & 3) + (j >> 2);
                float v = (tap < 25) ? wh[(og * 8 + icj) * 25 + tap] : 0.f;
                whF[i] = (_Float16)v;
            }
        } else if (b == 36 && tid < 32) {     // btot
            int og = (tid & 3) * 8 + (tid >> 2);
            btot[tid] = bx[og] + bh[og];
        }
    }

    // self-compute wk1 fragments (m=oc*4+pos, pr=2q+g, pc=j), then pin
    f16x8 wk1[3];
    {
        int m = lane & 31;
        #pragma unroll
        for (int q = 0; q < 3; ++q) {
            #pragma unroll
            for (int j = 0; j < 8; ++j) {
                int pr = 2 * q + g, pc = j;
                float v = 0.f;
                if (m < 16) {
                    int oc = m >> 2, qy = (m >> 1) & 1, qx = m & 1;
                    int ky = pr - qy, kx = pc - qx;
                    if ((unsigned)ky < 5u && (unsigned)kx < 5u)
                        v = w1[oc * 25 + ky * 5 + kx];
                }
                wk1[q][j] = (_Float16)v;
            }
        }
    }
    asm volatile("" : "+v"(wk1[0]), "+v"(wk1[1]), "+v"(wk1[2]));
    float bA = b1[g], bB = b1[g + 2];

    // stage input rows 8yt-2 .. 8yt+9 (12 rows), zero-padded
    for (int i = tid; i < 12 * 64; i += 256) {
        int r = i >> 6, c4 = i & 63;
        int gy = (yt << 3) - 2 + r;
        float4 v = make_float4(0.f, 0.f, 0.f, 0.f);
        if ((unsigned)gy < 256u)
            v = *(const float4*)(in + (gy << 8) + (c4 << 2));
        PK p0, p1;
        p0.h[0] = (_Float16)v.x; p0.h[1] = (_Float16)v.y;
        p1.h[0] = (_Float16)v.z; p1.h[1] = (_Float16)v.w;
        int ui = r * 132 + 1 + 2 * c4;
        ldsu[ui]     = p0.u;
        ldsu[ui + 1] = p1.u;
    }
    if (tid < 48) {    // halo u32s {0,129,130,131} per row
        int r = tid >> 2, c = tid & 3;
        int idx = (c == 0) ? 0 : 128 + c;
        ldsu[r * 132 + idx] = 0;
    }
    __syncthreads();

    // wave w -> pooled row 4yt+w; 4 col-tiles (max ILP variant)
    int y0p = yt << 2;
    #pragma unroll
    for (int i = 0; i < 4; ++i) {
        int n = (i << 5) + (lane & 31);      // pooled col 0..127
        const u32* lp = ldsu + (2 * w + g) * 132 + n;

        f32x16 acc;
        #pragma unroll
        for (int r = 0; r < 16; ++r) acc[r] = 0.f;

        #pragma unroll
        for (int q = 0; q < 3; ++q) {
            union { f16x8 v; u32 u[4]; } bb;
            const u32* p = lp + (2 * q) * 132;
            bb.u[0] = p[0]; bb.u[1] = p[1]; bb.u[2] = p[2]; bb.u[3] = p[3];
            acc = __builtin_amdgcn_mfma_f32_32x32x16_f16(wk1[q], bb.v, acc, 0, 0, 0);
        }

        float mA = fmaxf(fmaxf(fmaxf(acc[0], acc[1]), fmaxf(acc[2], acc[3])) + bA, 0.f);
        float mB = fmaxf(fmaxf(fmaxf(acc[4], acc[5]), fmaxf(acc[6], acc[7])) + bB, 0.f);

        PK pk;
        pk.h[0] = (_Float16)mA;
        pk.h[1] = (_Float16)mB;
        u32 part = (u32)__shfl_xor((int)pk.u, 32);
        if (g == 0) {
            PK pp; pp.u = part;
            f16x4 ov;
            ov[0] = pk.h[0]; ov[1] = pp.h[0];
            ov[2] = pk.h[1]; ov[3] = pp.h[1];
            int pix = ((y0p + w) << 7) + n;
            *(f16x4*)(s1cl + (((size_t)tb << 14) + pix) * 4) = ov;
        }
    }
}

// ---------------------------------------------------------------------------
// k2: conv 4->4 + relu + maxpool2 as MFMA (pool-in-M), coalesced store.
// r14-verified verbatim.
// ---------------------------------------------------------------------------
__global__ __launch_bounds__(256) void k2_mfma(
    const _Float16* __restrict__ s1cl, const _Float16* __restrict__ w2F,
    const float* __restrict__ b2, _Float16* __restrict__ s2cl)
{
    __shared__ _Float16 lds[20 * 136 * 4];
    int tid = threadIdx.x;
    int lane = tid & 63, w = tid >> 6, g = lane >> 5;
    int f  = blockIdx.x >> 3;
    int yt = blockIdx.x & 7;
    int y0 = yt << 3;

    f16x8 wf[12];
    #pragma unroll
    for (int q = 0; q < 12; ++q)
        wf[q] = *(const f16x8*)(w2F + ((size_t)q * 64 + lane) * 8);

    float bA = b2[g], bB = b2[g + 2];

    for (int i = tid; i < 20 * 68; i += 256) {
        int r = i / 68, u = i % 68;
        int gy = (yt << 4) - 2 + r;
        int gx = 2 * u - 2;
        f16x8 v = f16x8_zero();
        if ((unsigned)gy < 128u && (unsigned)gx < 127u)
            v = *(const f16x8*)(s1cl + ((((size_t)f << 14) + (gy << 7) + gx) << 2));
        *(f16x8*)&lds[(r * 136 + 2 * u) * 4] = v;
    }
    __syncthreads();

    #pragma unroll
    for (int i = 0; i < 4; ++i) {
        int ct = w * 4 + i;
        int ly = ct >> 1, hx = ct & 1;
        int px = hx * 32 + (lane & 31);
        int base = (2 * ly) * 1088 + (2 * px) * 8 + g * 16;

        f32x16 acc;
        #pragma unroll
        for (int r = 0; r < 16; ++r) acc[r] = 0.f;

        #pragma unroll
        for (int q = 0; q < 12; ++q) {
            f16x8 bv = *(const f16x8*)((const char*)lds + base +
                                       ((q >> 1) * 1088 + (q & 1) * 32));
            acc = __builtin_amdgcn_mfma_f32_32x32x16_f16(wf[q], bv, acc, 0, 0, 0);
        }

        float mA = fmaxf(fmaxf(fmaxf(acc[0], acc[1]), fmaxf(acc[2], acc[3])) + bA, 0.f);
        float mB = fmaxf(fmaxf(fmaxf(acc[4], acc[5]), fmaxf(acc[6], acc[7])) + bB, 0.f);

        PK pk;
        pk.h[0] = (_Float16)mA;
        pk.h[1] = (_Float16)mB;
        u32 part = (u32)__shfl_xor((int)pk.u, 32);
        if (g == 0) {
            PK pp; pp.u = part;
            f16x4 ov;
            ov[0] = pk.h[0]; ov[1] = pp.h[0];
            ov[2] = pk.h[1]; ov[3] = pp.h[1];
            int pix = ((y0 + ly) << 6) + px;
            *(f16x4*)(s2cl + ((((size_t)f << 12) + pix) << 2)) = ov;
        }
    }
}

// ---------------------------------------------------------------------------
// k4x: one ConvLSTM step with k3 fused (r12 verified), `first` flag skips
// state reads (no zero-init memsets anywhere).
// ---------------------------------------------------------------------------
__global__ __launch_bounds__(256, 4) void k4x(
    const _Float16* __restrict__ s2t, const _Float16* __restrict__ hprev,
    const _Float16* __restrict__ wxF, const _Float16* __restrict__ whF,
    const float* __restrict__ btot, float* __restrict__ cfr,
    const float* __restrict__ wci, const float* __restrict__ wcf,
    const float* __restrict__ wco, _Float16* __restrict__ hnext,
    float* __restrict__ out_hc, int first, int last)
{
    __shared__ _Float16 sH[6 * 68 * 8];      // 6528 B, pitch 1088
    __shared__ _Float16 sS[6 * 72 * 4];      // 3456 B, pitch 576
    int tid = threadIdx.x;
    int lane = tid & 63, w = tid >> 6, g = lane >> 5;
    int b  = blockIdx.x >> 5;
    int y0 = (blockIdx.x & 31) << 1;

    int ly = w >> 1, hx = w & 1;
    int px = hx * 32 + (lane & 31);
    int pix = ((y0 + ly) << 6) + px;
    size_t tl = (size_t)b * 128 + (y0 + ly) * 2 + hx;

    float4 cv = make_float4(0.f, 0.f, 0.f, 0.f);
    if (!first) cv = *(const float4*)(cfr + tl * 256 + lane * 4);
    float pci[4], pcf[4], pco[4];
    #pragma unroll
    for (int cc = 0; cc < 4; ++cc) {
        int ppix = ((2 * cc + g) << 12) + pix;
        pci[cc] = wci[ppix];
        pcf[cc] = wcf[ppix];
        pco[cc] = wco[ppix];
    }

    for (int i = tid; i < 6 * 68; i += 256) {
        int r = i / 68, u = i % 68;
        int gy = y0 - 2 + r;
        int gx = u - 2;
        f16x8 v = f16x8_zero();
        if (!first && (unsigned)gy < 64u && (unsigned)gx < 64u)
            v = *(const f16x8*)(hprev + ((((size_t)b << 12) + (gy << 6) + gx) << 3));
        *(f16x8*)&sH[(r * 68 + u) * 8] = v;
    }
    for (int i = tid; i < 6 * 36; i += 256) {
        int r = i / 36, u = i % 36;
        int gy = y0 - 2 + r;
        int gx = 2 * u - 2;
        f16x8 v = f16x8_zero();
        if ((unsigned)gy < 64u && (unsigned)gx < 63u)
            v = *(const f16x8*)(s2t + ((((size_t)b << 12) + (gy << 6) + gx) << 2));
        *(f16x8*)&sS[(r * 72 + 2 * u) * 4] = v;
    }
    __syncthreads();

    f32x16 acc;
    #pragma unroll
    for (int r = 0; r < 16; ++r) {
        int row0 = (r & 3) + 8 * (r >> 2);
        acc[r] = g ? btot[row0 + 4] : btot[row0];
    }

    {
        int baseS = ly * 576 + px * 8 + g * 16;
        #pragma unroll
        for (int q = 0; q < 10; ++q) {
            f16x8 wv = *(const f16x8*)(wxF + ((size_t)q * 64 + lane) * 8);
            f16x8 bv = *(const f16x8*)((const char*)sS + baseS +
                                       ((q >> 1) * 576 + (q & 1) * 32));
            acc = __builtin_amdgcn_mfma_f32_32x32x16_f16(wv, bv, acc, 0, 0, 0);
        }
    }
    {
        int baseH = ly * 1088 + px * 16;
        #pragma unroll
        for (int q = 0; q < 14; ++q) {
            int t0 = 2 * q, t1 = 2 * q + 1;
            int o0 = TKY(t0) * 1088 + TKX(t0) * 16;
            int o1 = TKY(t1) * 1088 + TKX(t1) * 16;
            int toff = g ? o1 : o0;
            f16x8 wv = *(const f16x8*)(whF + ((size_t)q * 64 + lane) * 8);
            f16x8 bv = *(const f16x8*)((const char*)sH + baseH + toff);
            acc = __builtin_amdgcn_mfma_f32_32x32x16_f16(wv, bv, acc, 0, 0, 0);
        }
    }

    float cvv[4] = {cv.x, cv.y, cv.z, cv.w};
    float cn4[4];
    f16x4 hv;
    #pragma unroll
    for (int cc = 0; cc < 4; ++cc) {
        float c_old = cvv[cc];
        float i_ = fast_sigmoid(acc[4 * cc + 0] + c_old * pci[cc]);
        float f_ = fast_sigmoid(acc[4 * cc + 1] + c_old * pcf[cc]);
        float cn = f_ * c_old + i_ * fast_tanh(acc[4 * cc + 2]);
        float o_ = fast_sigmoid(acc[4 * cc + 3] + cn * pco[cc]);
        float hn = o_ * fast_tanh(cn);
        cn4[cc] = cn;
        hv[cc] = (_Float16)hn;
        if (last) {
            int ch = 2 * cc + g;
            size_t sidx = (((size_t)b * 8 + ch) << 12) + pix;
            out_hc[sidx] = hn;
            out_hc[sidx + 1048576] = cn;
        }
    }
    if (!last) {
        *(float4*)(cfr + tl * 256 + lane * 4) =
            make_float4(cn4[0], cn4[1], cn4[2], cn4[3]);
        *(f16x4*)(hnext + ((((size_t)b << 12) + pix) << 3) + 4 * g) = hv;
    }
}

// ---------------------------------------------------------------------------
extern "C" void kernel_launch(void* const* d_in, const int* in_sizes, int n_in,
                              void* d_out, int out_size, void* d_ws, size_t ws_size,
                              hipStream_t stream)
{
    const float* obs = (const float*)d_in[0];
    const float* w1  = (const float*)d_in[1];
    const float* b1  = (const float*)d_in[2];
    const float* w2  = (const float*)d_in[3];
    const float* b2  = (const float*)d_in[4];
    const float* wx  = (const float*)d_in[5];
    const float* bx  = (const float*)d_in[6];
    const float* wh  = (const float*)d_in[7];
    const float* bh  = (const float*)d_in[8];
    const float* wci = (const float*)d_in[9];
    const float* wcf = (const float*)d_in[10];
    const float* wco = (const float*)d_in[11];

    char* wsb = (char*)d_ws;
    // byte layout:
    //   [0, 33,554,432)             s1cl f16 [256][16384][4]
    //   [33,554,432, 41,943,040)    s2cl f16 [256][4096][4]
    //   [41,943,040, 44,040,192)    hA f16
    //   [44,040,192, 46,137,344)    hB f16
    //   [46,137,344, 50,331,648)    cfr f32 [4096 tl][64][4]
    //   [50,331,648, ...)           w2F, wxF, whF, btot
    _Float16* s1cl = (_Float16*)wsb;
    _Float16* s2cl = (_Float16*)(wsb + 33554432);
    _Float16* hA   = (_Float16*)(wsb + 41943040);
    _Float16* hB   = (_Float16*)(wsb + 44040192);
    float*    cfr  = (float*)(wsb + 46137344);
    _Float16* w2F  = (_Float16*)(wsb + 50331648);
    _Float16* wxF  = (_Float16*)(wsb + 50343936);
    _Float16* whF  = (_Float16*)(wsb + 50354176);
    float*    btot = (float*)(wsb + 50368512);

    k1_mfma<<<8192, 256, 0, stream>>>(obs, w1, w2, wx, wh, bx, bh, b1,
                                      w2F, wxF, whF, btot, s1cl);
    k2_mfma<<<2048, 256, 0, stream>>>(s1cl, w2F, b2, s2cl);

    float* outp = (float*)d_out;
    for (int t = 0; t < 8; ++t) {
        const _Float16* hp = (t & 1) ? hB : hA;
        _Float16*       hn = (t & 1) ? hA : hB;
        k4x<<<1024, 256, 0, stream>>>(
            s2cl + (size_t)t * 524288, hp, wxF, whF, btot, cfr,
            wci, wcf, wco, hn, outp, t == 0, t == 7);
    }
}

// Round 18
// 137.635 us; speedup vs baseline: 1.0534x; 1.0237x over previous
//
#include <hip/hip_runtime.h>
#include <math.h>

typedef _Float16 f16x8 __attribute__((ext_vector_type(8)));
typedef _Float16 f16x4 __attribute__((ext_vector_type(4)));
typedef float    f32x16 __attribute__((ext_vector_type(16)));
typedef unsigned int u32;

#define DEVINL __device__ __forceinline__

DEVINL float fast_sigmoid(float x) {
    x = fminf(fmaxf(x, -30.f), 30.f);
    return 1.0f / (1.0f + __expf(-x));
}
DEVINL float fast_tanh(float x) {
    x = fminf(fmaxf(x, -15.f), 15.f);
    float e = __expf(-2.f * x);
    return (1.f - e) / (1.f + e);
}
DEVINL f16x8 f16x8_zero() {
    f16x8 v;
    #pragma unroll
    for (int j = 0; j < 8; ++j) v[j] = (_Float16)0.f;
    return v;
}

#define TKY(t) ((t) < 25 ? (t) / 5 : 2)
#define TKX(t) ((t) < 25 ? (t) % 5 : 2)

// ---------------------------------------------------------------------------
// kT_prep: weight repack (r12-verified; state zero-init dropped — k4x's
// `first` flag makes it unnecessary).
// ---------------------------------------------------------------------------
__global__ void kT_prep(const float* __restrict__ w1, const float* __restrict__ w2,
                        const float* __restrict__ wx, const float* __restrict__ wh,
                        const float* __restrict__ bx, const float* __restrict__ bh,
                        _Float16* __restrict__ wk1F, _Float16* __restrict__ w2F,
                        _Float16* __restrict__ wxF, _Float16* __restrict__ whF,
                        float* __restrict__ btot)
{
    int t = blockIdx.x * 256 + threadIdx.x;
    int stride = gridDim.x * 256;

    for (int i = t; i < 3 * 512; i += stride) {       // wk1F
        int j = i & 7, l = (i >> 3) & 63, q = i >> 9;
        int g = l >> 5, m = l & 31;
        int pr = 2 * q + g, pc = j;
        float v = 0.f;
        if (m < 16) {
            int oc = m >> 2, qy = (m >> 1) & 1, qx = m & 1;
            int ky = pr - qy, kx = pc - qx;
            if ((unsigned)ky < 5u && (unsigned)kx < 5u)
                v = w1[oc * 25 + ky * 5 + kx];
        }
        wk1F[i] = (_Float16)v;
    }
    for (int i = t; i < 12 * 512; i += stride) {      // w2F
        int j = i & 7, l = (i >> 3) & 63, q = i >> 9;
        int g = l >> 5, m = l & 31;
        int k = q * 16 + g * 8 + j;
        int pr = k >> 5, pc = (k >> 2) & 7, ic = k & 3;
        float v = 0.f;
        if (m < 16) {
            int oc = m >> 2, qy = (m >> 1) & 1, qx = m & 1;
            int ky = pr - qy, kx = pc - qx;
            if ((unsigned)ky < 5u && (unsigned)kx < 5u)
                v = w2[(oc * 4 + ic) * 25 + ky * 5 + kx];
        }
        w2F[i] = (_Float16)v;
    }
    for (int i = t; i < 10 * 512; i += stride) {      // wxF
        int j = i & 7, l = (i >> 3) & 63, q = i >> 9;
        int g = l >> 5, m = l & 31;
        int k = q * 16 + g * 8 + j;
        int pr = k >> 5, pc = (k >> 2) & 7, ic = k & 3;
        int og = (m & 3) * 8 + (m >> 2);
        float v = (pr < 5 && pc < 5) ? wx[(og * 4 + ic) * 25 + pr * 5 + pc] : 0.f;
        wxF[i] = (_Float16)v;
    }
    for (int i = t; i < 14 * 512; i += stride) {      // whF (j = ch' order)
        int j = i & 7, l = (i >> 3) & 63, q = i >> 9;
        int g = l >> 5, m = l & 31;
        int og = (m & 3) * 8 + (m >> 2);
        int tap = 2 * q + g;
        int icj = 2 * (j & 3) + (j >> 2);
        float v = (tap < 25) ? wh[(og * 8 + icj) * 25 + tap] : 0.f;
        whF[i] = (_Float16)v;
    }
    if (t < 32) {
        int og = (t & 3) * 8 + (t >> 2);
        btot[t] = bx[og] + bh[og];
    }
}

// ---------------------------------------------------------------------------
// k1: conv 1->4 + relu + maxpool2 as MFMA (pool-in-M). r12/r8-verified
// structure (16 tiles/wave, 36-row staging) — best measured configuration.
// ---------------------------------------------------------------------------
__global__ __launch_bounds__(256, 4) void k1_mfma(
    const float* __restrict__ obs, const _Float16* __restrict__ wk1F,
    const float* __restrict__ b1, _Float16* __restrict__ s1cl)
{
    __shared__ _Float16 lds[36 * 264];
    u32* ldsu = (u32*)lds;
    int tid = threadIdx.x;
    int lane = tid & 63, w = tid >> 6, g = lane >> 5;
    int yt = blockIdx.x & 7;
    int tb = blockIdx.x >> 3;
    const float* in = obs + ((size_t)tb << 16);

    f16x8 wk1[3];
    #pragma unroll
    for (int q = 0; q < 3; ++q)
        wk1[q] = *(const f16x8*)(wk1F + ((size_t)q * 64 + lane) * 8);
    float bA = b1[g], bB = b1[g + 2];

    for (int i = tid; i < 36 * 132; i += 256) ldsu[i] = 0;
    __syncthreads();
    for (int i = tid; i < 36 * 64; i += 256) {
        int r = i >> 6, c4 = i & 63;
        int gy = (yt << 5) - 2 + r;
        if ((unsigned)gy < 256u) {
            float4 v = *(const float4*)(in + (gy << 8) + (c4 << 2));
            union { _Float16 h[2]; u32 u; } p0, p1;
            p0.h[0] = (_Float16)v.x; p0.h[1] = (_Float16)v.y;
            p1.h[0] = (_Float16)v.z; p1.h[1] = (_Float16)v.w;
            int ui = r * 132 + 1 + 2 * c4;
            ldsu[ui]     = p0.u;
            ldsu[ui + 1] = p1.u;
        }
    }
    __syncthreads();

    int y0 = yt << 4;
    #pragma unroll
    for (int i = 0; i < 16; ++i) {
        int py_loc = (w << 2) + (i >> 2);
        int px0 = (i & 3) << 5;
        int n = px0 + (lane & 31);
        const u32* lp = ldsu + (2 * py_loc + g) * 132 + n;

        f32x16 acc;
        #pragma unroll
        for (int r = 0; r < 16; ++r) acc[r] = 0.f;

        #pragma unroll
        for (int q = 0; q < 3; ++q) {
            union { f16x8 v; u32 u[4]; } bb;
            const u32* p = lp + (2 * q) * 132;
            bb.u[0] = p[0]; bb.u[1] = p[1]; bb.u[2] = p[2]; bb.u[3] = p[3];
            acc = __builtin_amdgcn_mfma_f32_32x32x16_f16(wk1[q], bb.v, acc, 0, 0, 0);
        }

        float mA = fmaxf(fmaxf(fmaxf(acc[0], acc[1]), fmaxf(acc[2], acc[3])) + bA, 0.f);
        float mB = fmaxf(fmaxf(fmaxf(acc[4], acc[5]), fmaxf(acc[6], acc[7])) + bB, 0.f);

        int pix = ((y0 + py_loc) << 7) + n;
        _Float16* dst = s1cl + (((size_t)tb << 14) + pix) * 4;
        dst[g]     = (_Float16)mA;
        dst[g + 2] = (_Float16)mB;
    }
}

// ---------------------------------------------------------------------------
// k2: conv 4->4 + relu + maxpool2 as MFMA (pool-in-M). r12/r8-verified.
// ---------------------------------------------------------------------------
__global__ __launch_bounds__(256) void k2_mfma(
    const _Float16* __restrict__ s1cl, const _Float16* __restrict__ w2F,
    const float* __restrict__ b2, _Float16* __restrict__ s2cl)
{
    __shared__ _Float16 lds[20 * 136 * 4];
    int tid = threadIdx.x;
    int lane = tid & 63, w = tid >> 6, g = lane >> 5;
    int f  = blockIdx.x >> 3;
    int yt = blockIdx.x & 7;
    int y0 = yt << 3;

    f16x8 wf[12];
    #pragma unroll
    for (int q = 0; q < 12; ++q)
        wf[q] = *(const f16x8*)(w2F + ((size_t)q * 64 + lane) * 8);

    float bA = b2[g], bB = b2[g + 2];

    for (int i = tid; i < 20 * 68; i += 256) {
        int r = i / 68, u = i % 68;
        int gy = (yt << 4) - 2 + r;
        int gx = 2 * u - 2;
        f16x8 v = f16x8_zero();
        if ((unsigned)gy < 128u && (unsigned)gx < 127u)
            v = *(const f16x8*)(s1cl + ((((size_t)f << 14) + (gy << 7) + gx) << 2));
        *(f16x8*)&lds[(r * 136 + 2 * u) * 4] = v;
    }
    __syncthreads();

    #pragma unroll
    for (int i = 0; i < 4; ++i) {
        int ct = w * 4 + i;
        int ly = ct >> 1, hx = ct & 1;
        int px = hx * 32 + (lane & 31);
        int base = (2 * ly) * 1088 + (2 * px) * 8 + g * 16;

        f32x16 acc;
        #pragma unroll
        for (int r = 0; r < 16; ++r) acc[r] = 0.f;

        #pragma unroll
        for (int q = 0; q < 12; ++q) {
            f16x8 bv = *(const f16x8*)((const char*)lds + base +
                                       ((q >> 1) * 1088 + (q & 1) * 32));
            acc = __builtin_amdgcn_mfma_f32_32x32x16_f16(wf[q], bv, acc, 0, 0, 0);
        }

        float mA = fmaxf(fmaxf(fmaxf(acc[0], acc[1]), fmaxf(acc[2], acc[3])) + bA, 0.f);
        float mB = fmaxf(fmaxf(fmaxf(acc[4], acc[5]), fmaxf(acc[6], acc[7])) + bB, 0.f);

        int pix = ((y0 + ly) << 6) + px;
        _Float16* dst = s2cl + ((((size_t)f << 12) + pix) << 2);
        dst[g]     = (_Float16)mA;
        dst[g + 2] = (_Float16)mB;
    }
}

// ---------------------------------------------------------------------------
// k4x: one ConvLSTM step with k3 fused (r12-verified), `first` flag skips
// state reads at t=0 (r13-verified) so no zero-init is needed anywhere.
// ---------------------------------------------------------------------------
__global__ __launch_bounds__(256, 4) void k4x(
    const _Float16* __restrict__ s2t, const _Float16* __restrict__ hprev,
    const _Float16* __restrict__ wxF, const _Float16* __restrict__ whF,
    const float* __restrict__ btot, float* __restrict__ cfr,
    const float* __restrict__ wci, const float* __restrict__ wcf,
    const float* __restrict__ wco, _Float16* __restrict__ hnext,
    float* __restrict__ out_hc, int first, int last)
{
    __shared__ _Float16 sH[6 * 68 * 8];      // 6528 B, pitch 1088
    __shared__ _Float16 sS[6 * 72 * 4];      // 3456 B, pitch 576
    int tid = threadIdx.x;
    int lane = tid & 63, w = tid >> 6, g = lane >> 5;
    int b  = blockIdx.x >> 5;
    int y0 = (blockIdx.x & 31) << 1;

    int ly = w >> 1, hx = w & 1;
    int px = hx * 32 + (lane & 31);
    int pix = ((y0 + ly) << 6) + px;
    size_t tl = (size_t)b * 128 + (y0 + ly) * 2 + hx;

    float4 cv = make_float4(0.f, 0.f, 0.f, 0.f);
    if (!first) cv = *(const float4*)(cfr + tl * 256 + lane * 4);
    float pci[4], pcf[4], pco[4];
    #pragma unroll
    for (int cc = 0; cc < 4; ++cc) {
        int ppix = ((2 * cc + g) << 12) + pix;
        pci[cc] = wci[ppix];
        pcf[cc] = wcf[ppix];
        pco[cc] = wco[ppix];
    }

    for (int i = tid; i < 6 * 68; i += 256) {
        int r = i / 68, u = i % 68;
        int gy = y0 - 2 + r;
        int gx = u - 2;
        f16x8 v = f16x8_zero();
        if (!first && (unsigned)gy < 64u && (unsigned)gx < 64u)
            v = *(const f16x8*)(hprev + ((((size_t)b << 12) + (gy << 6) + gx) << 3));
        *(f16x8*)&sH[(r * 68 + u) * 8] = v;
    }
    for (int i = tid; i < 6 * 36; i += 256) {
        int r = i / 36, u = i % 36;
        int gy = y0 - 2 + r;
        int gx = 2 * u - 2;
        f16x8 v = f16x8_zero();
        if ((unsigned)gy < 64u && (unsigned)gx < 63u)
            v = *(const f16x8*)(s2t + ((((size_t)b << 12) + (gy << 6) + gx) << 2));
        *(f16x8*)&sS[(r * 72 + 2 * u) * 4] = v;
    }
    __syncthreads();

    f32x16 acc;
    #pragma unroll
    for (int r = 0; r < 16; ++r) {
        int row0 = (r & 3) + 8 * (r >> 2);
        acc[r] = g ? btot[row0 + 4] : btot[row0];
    }

    {
        int baseS = ly * 576 + px * 8 + g * 16;
        #pragma unroll
        for (int q = 0; q < 10; ++q) {
            f16x8 wv = *(const f16x8*)(wxF + ((size_t)q * 64 + lane) * 8);
            f16x8 bv = *(const f16x8*)((const char*)sS + baseS +
                                       ((q >> 1) * 576 + (q & 1) * 32));
            acc = __builtin_amdgcn_mfma_f32_32x32x16_f16(wv, bv, acc, 0, 0, 0);
        }
    }
    {
        int baseH = ly * 1088 + px * 16;
        #pragma unroll
        for (int q = 0; q < 14; ++q) {
            int t0 = 2 * q, t1 = 2 * q + 1;
            int o0 = TKY(t0) * 1088 + TKX(t0) * 16;
            int o1 = TKY(t1) * 1088 + TKX(t1) * 16;
            int toff = g ? o1 : o0;
            f16x8 wv = *(const f16x8*)(whF + ((size_t)q * 64 + lane) * 8);
            f16x8 bv = *(const f16x8*)((const char*)sH + baseH + toff);
            acc = __builtin_amdgcn_mfma_f32_32x32x16_f16(wv, bv, acc, 0, 0, 0);
        }
    }

    float cvv[4] = {cv.x, cv.y, cv.z, cv.w};
    float cn4[4];
    f16x4 hv;
    #pragma unroll
    for (int cc = 0; cc < 4; ++cc) {
        float c_old = cvv[cc];
        float i_ = fast_sigmoid(acc[4 * cc + 0] + c_old * pci[cc]);
        float f_ = fast_sigmoid(acc[4 * cc + 1] + c_old * pcf[cc]);
        float cn = f_ * c_old + i_ * fast_tanh(acc[4 * cc + 2]);
        float o_ = fast_sigmoid(acc[4 * cc + 3] + cn * pco[cc]);
        float hn = o_ * fast_tanh(cn);
        cn4[cc] = cn;
        hv[cc] = (_Float16)hn;
        if (last) {
            int ch = 2 * cc + g;
            size_t sidx = (((size_t)b * 8 + ch) << 12) + pix;
            out_hc[sidx] = hn;
            out_hc[sidx + 1048576] = cn;
        }
    }
    if (!last) {
        *(float4*)(cfr + tl * 256 + lane * 4) =
            make_float4(cn4[0], cn4[1], cn4[2], cn4[3]);
        *(f16x4*)(hnext + ((((size_t)b << 12) + pix) << 3) + 4 * g) = hv;
    }
}

// ---------------------------------------------------------------------------
extern "C" void kernel_launch(void* const* d_in, const int* in_sizes, int n_in,
                              void* d_out, int out_size, void* d_ws, size_t ws_size,
                              hipStream_t stream)
{
    const float* obs = (const float*)d_in[0];
    const float* w1  = (const float*)d_in[1];
    const float* b1  = (const float*)d_in[2];
    const float* w2  = (const float*)d_in[3];
    const float* b2  = (const float*)d_in[4];
    const float* wx  = (const float*)d_in[5];
    const float* bx  = (const float*)d_in[6];
    const float* wh  = (const float*)d_in[7];
    const float* bh  = (const float*)d_in[8];
    const float* wci = (const float*)d_in[9];
    const float* wcf = (const float*)d_in[10];
    const float* wco = (const float*)d_in[11];

    char* wsb = (char*)d_ws;
    // byte layout:
    //   [0, 33,554,432)             s1cl f16 [256][16384][4]
    //   [33,554,432, 41,943,040)    s2cl f16 [256][4096][4]
    //   [41,943,040, 44,040,192)    hA f16
    //   [44,040,192, 46,137,344)    hB f16
    //   [46,137,344, 50,331,648)    cfr f32 [4096 tl][64][4]
    //   [50,331,648, ...)           w2F, wxF, whF, wk1F, btot
    _Float16* s1cl = (_Float16*)wsb;
    _Float16* s2cl = (_Float16*)(wsb + 33554432);
    _Float16* hA   = (_Float16*)(wsb + 41943040);
    _Float16* hB   = (_Float16*)(wsb + 44040192);
    float*    cfr  = (float*)(wsb + 46137344);
    _Float16* w2F  = (_Float16*)(wsb + 50331648);
    _Float16* wxF  = (_Float16*)(wsb + 50343936);
    _Float16* whF  = (_Float16*)(wsb + 50354176);
    _Float16* wk1F = (_Float16*)(wsb + 50368512);
    float*    btot = (float*)(wsb + 50371584);

    kT_prep<<<64, 256, 0, stream>>>(w1, w2, wx, wh, bx, bh,
                                    wk1F, w2F, wxF, whF, btot);

    k1_mfma<<<2048, 256, 0, stream>>>(obs, wk1F, b1, s1cl);
    k2_mfma<<<2048, 256, 0, stream>>>(s1cl, w2F, b2, s2cl);

    float* outp = (float*)d_out;
    for (int t = 0; t < 8; ++t) {
        const _Float16* hp = (t & 1) ? hB : hA;
        _Float16*       hn = (t & 1) ? hA : hB;
        k4x<<<1024, 256, 0, stream>>>(
            s2cl + (size_t)t * 524288, hp, wxF, whF, btot, cfr,
            wci, wcf, wco, hn, outp, t == 0, t == 7);
    }
}